// Round 8
// baseline (756.945 us; speedup 1.0000x reference)
//
#include <hip/hip_runtime.h>

// PureWaveAttention B=2,T=2048,D=1024,H=16,NW=64,HD=64 — fp32 I/O, all GEMMs
// on MFMA via 2-term fp16 split: a = hi + lo/2048 (lo stored x2048),
// C = hh(hi,hi) + mx(hi,lo + lo,hi)/2048. fp32-equivalent numerics.
// ROUND 8: GEMM main loops are LDS-FREE. A rows are wave-private and read
// directly from global (fp32, split in-reg); B is pre-transposed [n][k] in ws
// and fragment-loaded directly (16 rows x 64 B contiguous per wave-inst ->
// L1/L2 served). No barriers, no staging, no bank conflicts in hot loops.
// Pipeline:
//  0) wsplit: W{qf,qp,kf,kp,v,o} fp32[k][n] -> hi/lo fp16[n][k]
//  1) proj  (M_wave=32): qn/kn = normalize(sin(f*t+p)) -> fp16 [B,T,H*64]
//  2) vgemm (M_wave=16): v = x@Wv+bv -> fp32 in d_out (consumed pre-outgemm)
//  3) chunk_kv -> G; prefix -> M; attn_chunk -> att hi/lo fp16 (alias qnh/knh)
//  4) outgemm (M_wave=16): d_out = att@Wo+bo
// ws (56 MB): Wsplit 24 | qnh 8 | knh 8 | G 16. atthi aliases qnh, attlo knh
// (block (c,h) sole reader of its slab; stages to LDS before overwrite).

#define Bb 2
#define Tt 2048
#define Dd 1024
#define Hh 16
#define NC 32

typedef _Float16 half_t;
typedef _Float16 half8 __attribute__((ext_vector_type(8)));
typedef _Float16 half4h __attribute__((ext_vector_type(4)));
typedef float float4v __attribute__((ext_vector_type(4)));

#define MFMA16(a, b, c) __builtin_amdgcn_mfma_f32_16x16x32_f16((a), (b), (c), 0, 0, 0)

__device__ __forceinline__ void split8(const float* v, half8& hi, half8& lo) {
  #pragma unroll
  for (int i = 0; i < 8; ++i) {
    half_t h = (half_t)v[i];
    hi[i] = h;
    lo[i] = (half_t)((v[i] - (float)h) * 2048.f);
  }
}

// ---------------------------------------------------------------------------
// Kernel 0: split+transpose weights: W[k][n] fp32 -> hi[n][k], lo[n][k] fp16.
// Per matrix: hi at m*2097152 halves, lo at +1048576.
// ---------------------------------------------------------------------------
__global__ __launch_bounds__(256) void wsplit_kernel(
    const float* __restrict__ W0, const float* __restrict__ W1,
    const float* __restrict__ W2, const float* __restrict__ W3,
    const float* __restrict__ W4, const float* __restrict__ W5,
    half_t* __restrict__ WSP)
{
  __shared__ float Ld[64][68];
  const int tid = threadIdx.x;
  const int m = blockIdx.z;
  const float* W = (m == 0) ? W0 : (m == 1) ? W1 : (m == 2) ? W2
                 : (m == 3) ? W3 : (m == 4) ? W4 : W5;
  const int k0 = blockIdx.x * 64, n0 = blockIdx.y * 64;
  const int r = tid >> 2, c4 = (tid & 3) * 16;
  #pragma unroll
  for (int i = 0; i < 4; ++i)
    *(float4*)&Ld[r][c4 + i * 4] =
        *(const float4*)&W[(size_t)(k0 + r) * Dd + n0 + c4 + i * 4];
  __syncthreads();
  half_t* hi = WSP + (size_t)m * 2097152;
  half_t* lo = hi + 1048576;
  const int n = tid >> 2, kc = (tid & 3) * 16;
  half8 hv0, hv1, lv0, lv1;
  #pragma unroll
  for (int i = 0; i < 8; ++i) {
    float v0 = Ld[kc + i][n];
    half_t h0 = (half_t)v0;
    hv0[i] = h0; lv0[i] = (half_t)((v0 - (float)h0) * 2048.f);
    float v1 = Ld[kc + 8 + i][n];
    half_t h1 = (half_t)v1;
    hv1[i] = h1; lv1[i] = (half_t)((v1 - (float)h1) * 2048.f);
  }
  *(half8*)&hi[(size_t)(n0 + n) * Dd + k0 + kc]     = hv0;
  *(half8*)&hi[(size_t)(n0 + n) * Dd + k0 + kc + 8] = hv1;
  *(half8*)&lo[(size_t)(n0 + n) * Dd + k0 + kc]     = lv0;
  *(half8*)&lo[(size_t)(n0 + n) * Dd + k0 + kc + 8] = lv1;
}

// ---------------------------------------------------------------------------
// Kernel 1: proj, LDS-free. Block = 4 waves x M_wave=32 -> 128 t-rows.
// N=128 = F cols (tn 0..3) | P cols (tn 4..7) of one head. grid.z = b*2+p.
// ---------------------------------------------------------------------------
__global__ __launch_bounds__(256, 2) void proj_kernel(
    const float* __restrict__ X, const half_t* __restrict__ WSP,
    const float* __restrict__ bqf, const float* __restrict__ bqp,
    const float* __restrict__ bkf, const float* __restrict__ bkp,
    half_t* __restrict__ QNH, half_t* __restrict__ KNH)
{
  const int tid = threadIdx.x;
  const int lane = tid & 63, wave = tid >> 6;
  const int lm = lane & 15, lq = lane >> 4;
  const int mb = blockIdx.x, h = blockIdx.y;
  const int b = blockIdx.z >> 1, p = blockIdx.z & 1;
  const int t0 = mb * 128, col0 = h * 64;
  const half_t* WF = WSP + (size_t)(2 * p) * 2097152;   // hi; lo at +1048576
  const half_t* WP = WSP + (size_t)(2 * p + 1) * 2097152;
  const float* BF = p ? bkf : bqf;
  const float* BP = p ? bkp : bqp;
  half_t* OUTH = p ? KNH : QNH;

  const size_t r0 = (size_t)(b * Tt + t0 + wave * 32 + lm);
  const size_t r1 = r0 + 16;

  float4v hh[2][8], mx[2][8];
  #pragma unroll
  for (int m = 0; m < 2; ++m)
    #pragma unroll
    for (int i = 0; i < 8; ++i) {
      hh[m][i] = (float4v){0.f, 0.f, 0.f, 0.f};
      mx[m][i] = hh[m][i];
    }

  for (int k0 = 0; k0 < Dd; k0 += 32) {
    half8 ahi[2], alo[2];
    {
      float av[8];
      *(float4*)&av[0] = *(const float4*)&X[r0 * Dd + k0 + lq * 8];
      *(float4*)&av[4] = *(const float4*)&X[r0 * Dd + k0 + lq * 8 + 4];
      split8(av, ahi[0], alo[0]);
      *(float4*)&av[0] = *(const float4*)&X[r1 * Dd + k0 + lq * 8];
      *(float4*)&av[4] = *(const float4*)&X[r1 * Dd + k0 + lq * 8 + 4];
      split8(av, ahi[1], alo[1]);
    }
    #pragma unroll
    for (int tn = 0; tn < 8; ++tn) {
      const half_t* Wb = (tn < 4) ? WF : WP;
      const size_t nrow = (size_t)(col0 + (tn & 3) * 16 + lm);
      half8 bhi = *(const half8*)&Wb[nrow * Dd + k0 + lq * 8];
      half8 blo = *(const half8*)&Wb[1048576 + nrow * Dd + k0 + lq * 8];
      #pragma unroll
      for (int m = 0; m < 2; ++m) {
        hh[m][tn] = MFMA16(ahi[m], bhi, hh[m][tn]);
        mx[m][tn] = MFMA16(ahi[m], blo, mx[m][tn]);
        mx[m][tn] = MFMA16(alo[m], bhi, mx[m][tn]);
      }
    }
  }

  float fb[4], pb[4];
  #pragma unroll
  for (int j = 0; j < 4; ++j) {
    fb[j] = BF[col0 + j * 16 + lm];
    pb[j] = BP[col0 + j * 16 + lm];
  }
  #pragma unroll
  for (int m = 0; m < 2; ++m) {
    #pragma unroll
    for (int r = 0; r < 4; ++r) {
      const int t = t0 + wave * 32 + m * 16 + lq * 4 + r;
      const float tf = (float)t;
      float w[4]; float ss = 0.f;
      #pragma unroll
      for (int j = 0; j < 4; ++j) {
        float f  = hh[m][j][r]     + mx[m][j][r]     * (1.f / 2048.f) + fb[j];
        float pp = hh[m][4 + j][r] + mx[m][4 + j][r] * (1.f / 2048.f) + pb[j];
        w[j] = sinf(fmaf(f, tf, pp));
        ss += w[j] * w[j];
      }
      ss += __shfl_xor(ss, 1); ss += __shfl_xor(ss, 2);
      ss += __shfl_xor(ss, 4); ss += __shfl_xor(ss, 8);
      const float inv = 1.f / fmaxf(sqrtf(ss), 1e-12f);
      #pragma unroll
      for (int j = 0; j < 4; ++j)
        OUTH[(size_t)(b * Tt + t) * Dd + col0 + j * 16 + lm] = (half_t)(w[j] * inv);
    }
  }
}

// ---------------------------------------------------------------------------
// Kernel 2/4: LDS-free GEMM C[M,1024] = A@W + bias. M_wave=16, block M=64,
// N-tile 128. A fp32 (split on fly) or pre-split halves.
// ---------------------------------------------------------------------------
template<bool AF32>
__global__ __launch_bounds__(256, 2) void gemm_direct_kernel(
    const float* __restrict__ A32,
    const half_t* __restrict__ AHI, const half_t* __restrict__ ALO,
    const half_t* __restrict__ WHI,   // lo at +1048576
    const float* __restrict__ BIAS, float* __restrict__ OUT)
{
  const int tid = threadIdx.x;
  const int lane = tid & 63, wave = tid >> 6;
  const int lm = lane & 15, lq = lane >> 4;
  const int n0 = blockIdx.y * 128;
  const size_t row = (size_t)(blockIdx.x * 64 + wave * 16 + lm);

  float4v hh[8], mx[8];
  #pragma unroll
  for (int i = 0; i < 8; ++i) {
    hh[i] = (float4v){0.f, 0.f, 0.f, 0.f};
    mx[i] = hh[i];
  }

  for (int k0 = 0; k0 < Dd; k0 += 32) {
    half8 ahi, alo;
    if constexpr (AF32) {
      float av[8];
      *(float4*)&av[0] = *(const float4*)&A32[row * Dd + k0 + lq * 8];
      *(float4*)&av[4] = *(const float4*)&A32[row * Dd + k0 + lq * 8 + 4];
      split8(av, ahi, alo);
    } else {
      ahi = *(const half8*)&AHI[row * Dd + k0 + lq * 8];
      alo = *(const half8*)&ALO[row * Dd + k0 + lq * 8];
    }
    #pragma unroll
    for (int tn = 0; tn < 8; ++tn) {
      const size_t nrow = (size_t)(n0 + tn * 16 + lm);
      half8 bhi = *(const half8*)&WHI[nrow * Dd + k0 + lq * 8];
      half8 blo = *(const half8*)&WHI[1048576 + nrow * Dd + k0 + lq * 8];
      hh[tn] = MFMA16(ahi, bhi, hh[tn]);
      mx[tn] = MFMA16(ahi, blo, mx[tn]);
      mx[tn] = MFMA16(alo, bhi, mx[tn]);
    }
  }

  #pragma unroll
  for (int tn = 0; tn < 8; ++tn) {
    const float bn = BIAS[n0 + tn * 16 + lm];
    #pragma unroll
    for (int r = 0; r < 4; ++r) {
      const size_t orow = (size_t)(blockIdx.x * 64 + wave * 16 + lq * 4 + r);
      OUT[orow * Dd + n0 + tn * 16 + lm] =
          hh[tn][r] + mx[tn][r] * (1.f / 2048.f) + bn;
    }
  }
}

// ---------------------------------------------------------------------------
// Kernel 3a: G_c[w][d] = sum_{s in c} K[s][w]*V[s][d]. K from fp16, V fp32.
// ---------------------------------------------------------------------------
__global__ __launch_bounds__(256) void chunk_kv_kernel(
    const half_t* __restrict__ KNH, const float* __restrict__ V,
    float* __restrict__ G)
{
  __shared__ float Ks[64][64];
  __shared__ float Vs[64][64];
  const int tid = threadIdx.x;
  const int c = blockIdx.x, h = blockIdx.y, b = blockIdx.z;
  const int s0 = c * 64;
  const int lr = tid >> 2, lc = (tid & 3) * 16;
  {
    const half_t* krow = &KNH[(size_t)(b * Tt + s0 + lr) * Dd + h * 64 + lc];
    half8 ka = *(const half8*)&krow[0];
    half8 kb = *(const half8*)&krow[8];
    #pragma unroll
    for (int i = 0; i < 8; ++i) {
      Ks[lr][lc + i] = (float)ka[i];
      Ks[lr][lc + 8 + i] = (float)kb[i];
    }
    const float* vrow = &V[(size_t)(b * Tt + s0 + lr) * Dd + h * 64 + lc];
    #pragma unroll
    for (int i = 0; i < 4; ++i)
      *(float4*)&Vs[lr][lc + i * 4] = *(const float4*)&vrow[i * 4];
  }
  __syncthreads();

  const int ty = tid >> 4, tx = tid & 15;
  float g[4][4] = {{0.f}};
  #pragma unroll 4
  for (int s = 0; s < 64; ++s) {
    float4 kv = *(const float4*)&Ks[s][ty * 4];
    float4 vv = *(const float4*)&Vs[s][tx * 4];
    const float* k_ = (const float*)&kv;
    const float* v_ = (const float*)&vv;
    #pragma unroll
    for (int i = 0; i < 4; ++i)
      #pragma unroll
      for (int j = 0; j < 4; ++j)
        g[i][j] = fmaf(k_[i], v_[j], g[i][j]);
  }
  float* Gp = G + (((size_t)(b * Hh + h) * NC + c) << 12);
  #pragma unroll
  for (int i = 0; i < 4; ++i)
    *(float4*)&Gp[(ty * 4 + i) * 64 + tx * 4] =
        make_float4(g[i][0], g[i][1], g[i][2], g[i][3]);
}

// ---------------------------------------------------------------------------
// Kernel 3b: in-place exclusive prefix over NC chunk matrices per (b,h).
// ---------------------------------------------------------------------------
__global__ __launch_bounds__(256) void prefix_kernel(float* __restrict__ G)
{
  const int h = blockIdx.x, b = blockIdx.y;
  float* base = G + (((size_t)(b * Hh + h) * NC) << 12);
  const int off = threadIdx.x * 16;
  float4 a0 = make_float4(0.f, 0.f, 0.f, 0.f);
  float4 a1 = a0, a2 = a0, a3 = a0;
  for (int c = 0; c < NC; ++c) {
    float* p = base + ((size_t)c << 12) + off;
    float4 g0 = *(float4*)&p[0];
    float4 g1 = *(float4*)&p[4];
    float4 g2 = *(float4*)&p[8];
    float4 g3 = *(float4*)&p[12];
    *(float4*)&p[0] = a0; *(float4*)&p[4] = a1;
    *(float4*)&p[8] = a2; *(float4*)&p[12] = a3;
    a0.x += g0.x; a0.y += g0.y; a0.z += g0.z; a0.w += g0.w;
    a1.x += g1.x; a1.y += g1.y; a1.z += g1.z; a1.w += g1.w;
    a2.x += g2.x; a2.y += g2.y; a2.z += g2.z; a2.w += g2.w;
    a3.x += g3.x; a3.y += g3.y; a3.z += g3.z; a3.w += g3.w;
  }
}

// ---------------------------------------------------------------------------
// Kernel 3c: O_c = (Q_c M_c + tril(Q_c K_c^T) V_c) * scale/sqrt(t+1).
// Q,K from fp16; out split to fp16 hi/lo (lo x2048), aliasing qnh/knh.
// ---------------------------------------------------------------------------
__global__ __launch_bounds__(256) void attn_chunk_kernel(
    const half_t* __restrict__ QNH, const half_t* __restrict__ KNH,
    const float* __restrict__ V, const float* __restrict__ M,
    const float* __restrict__ SCALE,
    half_t* __restrict__ ATTHI, half_t* __restrict__ ATTLO)
{
  __shared__ float Qt[64][68];
  __shared__ float Kt[64][68];
  __shared__ float SM[64][68];
  __shared__ float Vs[64][64];
  const int tid = threadIdx.x;
  const int c = blockIdx.x, h = blockIdx.y, b = blockIdx.z;
  const int t0 = c * 64;
  const int lr = tid >> 2, lc = (tid & 3) * 16;
  {
    const half_t* qrow = &QNH[(size_t)(b * Tt + t0 + lr) * Dd + h * 64 + lc];
    const half_t* krow = &KNH[(size_t)(b * Tt + t0 + lr) * Dd + h * 64 + lc];
    half8 qa = *(const half8*)&qrow[0];
    half8 qb = *(const half8*)&qrow[8];
    half8 ka = *(const half8*)&krow[0];
    half8 kb = *(const half8*)&krow[8];
    #pragma unroll
    for (int i = 0; i < 8; ++i) {
      Qt[lc + i][lr] = (float)qa[i];     Qt[lc + 8 + i][lr] = (float)qb[i];
      Kt[lc + i][lr] = (float)ka[i];     Kt[lc + 8 + i][lr] = (float)kb[i];
    }
    const float* vrow = &V[(size_t)(b * Tt + t0 + lr) * Dd + h * 64 + lc];
    const float* mrow = &M[(((size_t)(b * Hh + h) * NC + c) << 12) + lr * 64 + lc];
    #pragma unroll
    for (int i = 0; i < 4; ++i) {
      *(float4*)&Vs[lr][lc + i * 4] = *(const float4*)&vrow[i * 4];
      *(float4*)&SM[lr][lc + i * 4] = *(const float4*)&mrow[i * 4];
    }
  }
  __syncthreads();

  const int ty = tid >> 4, tx = tid & 15;
  float o[4][4] = {{0.f}};
  float sc[4][4] = {{0.f}};

  #pragma unroll 4
  for (int w = 0; w < 64; ++w) {
    float4 qv = *(const float4*)&Qt[w][ty * 4];
    float4 mv = *(const float4*)&SM[w][tx * 4];
    float4 kv = *(const float4*)&Kt[w][tx * 4];
    const float* q_ = (const float*)&qv;
    const float* m_ = (const float*)&mv;
    const float* k_ = (const float*)&kv;
    #pragma unroll
    for (int i = 0; i < 4; ++i) {
      float qq = q_[i];
      #pragma unroll
      for (int j = 0; j < 4; ++j) {
        o[i][j]  = fmaf(qq, m_[j], o[i][j]);
        sc[i][j] = fmaf(qq, k_[j], sc[i][j]);
      }
    }
  }
  __syncthreads();

  #pragma unroll
  for (int i = 0; i < 4; ++i) {
    const int lt = ty * 4 + i;
    #pragma unroll
    for (int j = 0; j < 4; ++j) {
      const int ls = tx * 4 + j;
      SM[ls][lt] = (ls <= lt) ? sc[i][j] : 0.f;
    }
  }
  __syncthreads();

  #pragma unroll 4
  for (int s = 0; s < 64; ++s) {
    float4 sv = *(const float4*)&SM[s][ty * 4];
    float4 vv = *(const float4*)&Vs[s][tx * 4];
    const float* s_ = (const float*)&sv;
    const float* v_ = (const float*)&vv;
    #pragma unroll
    for (int i = 0; i < 4; ++i)
      #pragma unroll
      for (int j = 0; j < 4; ++j)
        o[i][j] = fmaf(s_[i], v_[j], o[i][j]);
  }

  const float sch = SCALE[h];
  #pragma unroll
  for (int i = 0; i < 4; ++i) {
    const int t = t0 + ty * 4 + i;
    const float fac = sch / sqrtf((float)(t + 1));
    half4h hv, lv;
    #pragma unroll
    for (int j = 0; j < 4; ++j) {
      float v = o[i][j] * fac;
      half_t hx = (half_t)v;
      hv[j] = hx; lv[j] = (half_t)((v - (float)hx) * 2048.f);
    }
    *(half4h*)&ATTHI[(size_t)(b * Tt + t) * Dd + h * 64 + tx * 4] = hv;
    *(half4h*)&ATTLO[(size_t)(b * Tt + t) * Dd + h * 64 + tx * 4] = lv;
  }
}

// ---------------------------------------------------------------------------
extern "C" void kernel_launch(void* const* d_in, const int* in_sizes, int n_in,
                              void* d_out, int out_size, void* d_ws, size_t ws_size,
                              hipStream_t stream) {
  const float* x   = (const float*)d_in[0];
  const float* Wqf = (const float*)d_in[1];
  const float* bqf = (const float*)d_in[2];
  const float* Wkf = (const float*)d_in[3];
  const float* bkf = (const float*)d_in[4];
  const float* Wqp = (const float*)d_in[5];
  const float* bqp = (const float*)d_in[6];
  const float* Wkp = (const float*)d_in[7];
  const float* bkp = (const float*)d_in[8];
  const float* Wv  = (const float*)d_in[9];
  const float* bv  = (const float*)d_in[10];
  const float* Wo  = (const float*)d_in[11];
  const float* bo  = (const float*)d_in[12];
  const float* scale = (const float*)d_in[13];

  // ws layout (56 MB): Wsplit 24 MB | qnh 8 MB | knh 8 MB | G 16 MB
  half_t* WSP = (half_t*)d_ws;
  half_t* qnh = WSP + 12582912;
  half_t* knh = qnh + 4194304;
  float*  G   = (float*)(knh + 4194304);
  float*  vbuf = (float*)d_out;   // v lives in d_out, consumed before outgemm

  // mat order in WSP: 0=qf 1=qp 2=kf 3=kp 4=v 5=o
  wsplit_kernel<<<dim3(16, 16, 6), 256, 0, stream>>>(Wqf, Wqp, Wkf, Wkp, Wv, Wo, WSP);

  proj_kernel<<<dim3(Tt / 128, Hh, Bb * 2), 256, 0, stream>>>(
      x, WSP, bqf, bqp, bkf, bkp, qnh, knh);

  gemm_direct_kernel<true><<<dim3((Bb * Tt) / 64, Dd / 128), 256, 0, stream>>>(
      x, nullptr, nullptr, WSP + (size_t)4 * 2097152, bv, vbuf);

  chunk_kv_kernel<<<dim3(NC, Hh, Bb), 256, 0, stream>>>(knh, vbuf, G);
  prefix_kernel<<<dim3(Hh, Bb), 256, 0, stream>>>(G);
  attn_chunk_kernel<<<dim3(NC, Hh, Bb), 256, 0, stream>>>(
      qnh, knh, vbuf, G, scale, qnh /*atthi*/, knh /*attlo*/);

  gemm_direct_kernel<false><<<dim3((Bb * Tt) / 64, Dd / 128), 256, 0, stream>>>(
      nullptr, qnh, knh, WSP + (size_t)5 * 2097152, bo, (float*)d_out);
}

// Round 9
// 489.570 us; speedup vs baseline: 1.5461x; 1.5461x over previous
//
#include <hip/hip_runtime.h>

// PureWaveAttention B=2,T=2048,D=1024,H=16,NW=64,HD=64 — fp32 I/O, GEMMs on
// MFMA via 2-term fp16 split: a = hi + lo/2048 (lo stored x2048),
// C = hh(hi,hi) + mx(hi,lo)+mx(lo,hi) /2048. fp32-equivalent numerics.
// ROUND 9: B staged in LDS in FRAGMENT-LINEAR chunk order (contiguous copy,
// uniform-minimum bank pattern); A direct from global (wave-private rows);
// 2x2 wave tiling, a=4 x b=4 frags -> 48 MFMA per 8 LDS reads (MFMA-bound).
// WSP chunk layout per (nb, slab s): [hp(hi/lo)][c = tn*64+lq*16+lm] half8,
//   chunk = W[k=s*32+lq*8 .. +7][col = nb*W + tn*16+lm]  (B-operand frag).
// Regions (halves): Q(fused qf|qp per head, 128 cols/blk) @0, K @4194304,
//   V(64 cols/blk) @8388608, O @10485760. Total 24 MB.
// Pipeline: wsplit -> proj -> vgemm(v in d_out) -> chunk_kv -> prefix ->
//   attn_chunk (att hi/lo fp16, alias qnh/knh) -> outgemm.
// ws (56 MB): WSP 24 | qnh 8 | knh 8 | G 16.

#define Bb 2
#define Tt 2048
#define Dd 1024
#define Hh 16
#define NC 32

typedef _Float16 half_t;
typedef _Float16 half8 __attribute__((ext_vector_type(8)));
typedef _Float16 half4h __attribute__((ext_vector_type(4)));
typedef float float4v __attribute__((ext_vector_type(4)));

#define MFMA16(a, b, c) __builtin_amdgcn_mfma_f32_16x16x32_f16((a), (b), (c), 0, 0, 0)

#define QBASE 0u
#define KBASE 4194304u
#define VBASE 8388608u
#define OBASE 10485760u

__device__ __forceinline__ void split8(const float* v, half8& hi, half8& lo) {
  #pragma unroll
  for (int i = 0; i < 8; ++i) {
    half_t h = (half_t)v[i];
    hi[i] = h;
    lo[i] = (half_t)((v[i] - (float)h) * 2048.f);
  }
}

// ---------------------------------------------------------------------------
// Kernel 0: wsplit -> fragment-linear chunk layout.
// grid (s=32, blk=64): blk 0..15 Q(h), 16..31 K(h), 32..47 V(nb), 48..63 O(nb).
// ---------------------------------------------------------------------------
__global__ __launch_bounds__(256) void wsplit_kernel(
    const float* __restrict__ Wqf, const float* __restrict__ Wqp,
    const float* __restrict__ Wkf, const float* __restrict__ Wkp,
    const float* __restrict__ Wv,  const float* __restrict__ Wo,
    half_t* __restrict__ WSP)
{
  __shared__ float Ld[32][130];
  const int tid = threadIdx.x;
  const int s = blockIdx.x, blk = blockIdx.y;

  const float *SF, *SP;
  size_t baseh; int ncols, hb;
  if (blk < 16)      { hb = blk;      SF = Wqf; SP = Wqp; ncols = 128;
                       baseh = QBASE + (size_t)(hb * 32 + s) * 8192; }
  else if (blk < 32) { hb = blk - 16; SF = Wkf; SP = Wkp; ncols = 128;
                       baseh = KBASE + (size_t)(hb * 32 + s) * 8192; }
  else if (blk < 48) { hb = blk - 32; SF = Wv;  SP = nullptr; ncols = 64;
                       baseh = VBASE + (size_t)(hb * 32 + s) * 4096; }
  else               { hb = blk - 48; SF = Wo;  SP = nullptr; ncols = 64;
                       baseh = OBASE + (size_t)(hb * 32 + s) * 4096; }

  // load 32k x ncols fp32, coalesced along cols
  if (ncols == 128) {
    #pragma unroll
    for (int j = 0; j < 4; ++j) {
      const int idx = tid + j * 256;           // < 1024
      const int kr = idx >> 5, c4 = (idx & 31) * 4;
      const float* src = (c4 < 64) ? SF : SP;
      const int cg = hb * 64 + (c4 & 63);
      *(float4*)&Ld[kr][c4] = *(const float4*)&src[(size_t)(s * 32 + kr) * Dd + cg];
    }
  } else {
    #pragma unroll
    for (int j = 0; j < 2; ++j) {
      const int idx = tid + j * 256;           // < 512
      const int kr = idx >> 4, c4 = (idx & 15) * 4;
      const int cg = hb * 64 + c4;
      *(float4*)&Ld[kr][c4] = *(const float4*)&SF[(size_t)(s * 32 + kr) * Dd + cg];
    }
  }
  __syncthreads();

  const int nch2 = (ncols == 128) ? 1024 : 512;   // hp*half + c
  const int halfn = nch2 >> 1;
  for (int j = 0; j < 4; ++j) {
    const int idx = tid + j * 256;
    if (idx >= nch2) break;
    const int hp = (idx >= halfn);
    const int c = idx - hp * halfn;
    const int tn = c >> 6, lq = (c >> 4) & 3, lm = c & 15;
    const int col = tn * 16 + lm;
    half8 outv;
    #pragma unroll
    for (int i = 0; i < 8; ++i) {
      float v = Ld[lq * 8 + i][col];
      half_t h = (half_t)v;
      outv[i] = hp ? (half_t)((v - (float)h) * 2048.f) : h;
    }
    *(half8*)&WSP[baseh + (size_t)idx * 8] = outv;
  }
}

// ---------------------------------------------------------------------------
// Kernel 1: proj. grid (mb=16, h=16, z=4: b*2+p). 4 waves 2m x 2n.
// Wave (wm,wn): rows wm*64 + i*16+lm (i<4, direct global); tn set
// {2wn,2wn+1,2wn+4,2wn+5} -> lane holds matching (f,p) cols.
// Epilogue: sin(f*t+p), cross-wave norm via 1KB LDS, fp16 out.
// ---------------------------------------------------------------------------
__global__ __launch_bounds__(256, 2) void proj_kernel(
    const float* __restrict__ X, const half_t* __restrict__ WSP,
    const float* __restrict__ bqf, const float* __restrict__ bqp,
    const float* __restrict__ bkf, const float* __restrict__ bkp,
    half_t* __restrict__ QNH, half_t* __restrict__ KNH)
{
  __shared__ half_t Bs[8192];        // 16 KB: 1024 chunks
  __shared__ float ssb[2][128];
  const int tid = threadIdx.x;
  const int lane = tid & 63, wave = tid >> 6;
  const int lm = lane & 15, lq = lane >> 4;
  const int wm = wave >> 1, wn = wave & 1;
  const int mb = blockIdx.x, h = blockIdx.y;
  const int b = blockIdx.z >> 1, p = blockIdx.z & 1;
  const int col0 = h * 64;
  const size_t pb = (p ? KBASE : QBASE) + (size_t)h * 32 * 8192;
  const float* BF = p ? bkf : bqf;
  const float* BP = p ? bkp : bqp;
  half_t* OUTH = p ? KNH : QNH;

  const float* Ap[4];
  #pragma unroll
  for (int i = 0; i < 4; ++i)
    Ap[i] = X + (size_t)(b * Tt + mb * 128 + wm * 64 + i * 16 + lm) * Dd;

  float4v hh[4][4], mx[4][4];
  #pragma unroll
  for (int i = 0; i < 4; ++i)
    #pragma unroll
    for (int t = 0; t < 4; ++t) {
      hh[i][t] = (float4v){0.f, 0.f, 0.f, 0.f};
      mx[i][t] = hh[i][t];
    }

  int tg[4];
  #pragma unroll
  for (int t = 0; t < 4; ++t) tg[t] = 2 * wn + (t & 1) + (t >> 1) * 4;

  half8 rs[4];
  #pragma unroll
  for (int j = 0; j < 4; ++j)
    rs[j] = *(const half8*)&WSP[pb + (size_t)(tid + j * 256) * 8];

  for (int s = 0; s < 32; ++s) {
    #pragma unroll
    for (int j = 0; j < 4; ++j)
      *(half8*)&Bs[(tid + j * 256) * 8] = rs[j];
    __syncthreads();
    if (s < 31) {
      const size_t nb = pb + (size_t)(s + 1) * 8192;
      #pragma unroll
      for (int j = 0; j < 4; ++j)
        rs[j] = *(const half8*)&WSP[nb + (size_t)(tid + j * 256) * 8];
    }
    half8 ahi[4], alo[4];
    #pragma unroll
    for (int i = 0; i < 4; ++i) {
      float av[8];
      *(float4*)&av[0] = *(const float4*)&Ap[i][s * 32 + lq * 8];
      *(float4*)&av[4] = *(const float4*)&Ap[i][s * 32 + lq * 8 + 4];
      split8(av, ahi[i], alo[i]);
    }
    #pragma unroll
    for (int t = 0; t < 4; ++t) {
      const int ci = tg[t] * 64 + lq * 16 + lm;
      half8 bhi = *(const half8*)&Bs[ci * 8];
      half8 blo = *(const half8*)&Bs[(512 + ci) * 8];
      #pragma unroll
      for (int i = 0; i < 4; ++i) {
        hh[i][t] = MFMA16(ahi[i], bhi, hh[i][t]);
        mx[i][t] = MFMA16(ahi[i], blo, mx[i][t]);
        mx[i][t] = MFMA16(alo[i], bhi, mx[i][t]);
      }
    }
    __syncthreads();
  }

  // epilogue: lane col j = 32*wn + 16*e + lm (e=0,1); f=acc[e], p=acc[2+e]
  float fb[2], pb2[2];
  #pragma unroll
  for (int e = 0; e < 2; ++e) {
    fb[e]  = BF[col0 + 32 * wn + 16 * e + lm];
    pb2[e] = BP[col0 + 32 * wn + 16 * e + lm];
  }
  #pragma unroll
  for (int i = 0; i < 4; ++i) {
    #pragma unroll
    for (int r = 0; r < 4; ++r) {
      const int rl = wm * 64 + i * 16 + lq * 4 + r;
      const int t = mb * 128 + rl;
      const float tf = (float)t;
      float w0, w1;
      {
        float f0 = hh[i][0][r] + mx[i][0][r] * (1.f / 2048.f) + fb[0];
        float p0 = hh[i][2][r] + mx[i][2][r] * (1.f / 2048.f) + pb2[0];
        w0 = sinf(fmaf(f0, tf, p0));
        float f1 = hh[i][1][r] + mx[i][1][r] * (1.f / 2048.f) + fb[1];
        float p1 = hh[i][3][r] + mx[i][3][r] * (1.f / 2048.f) + pb2[1];
        w1 = sinf(fmaf(f1, tf, p1));
      }
      float ss = w0 * w0 + w1 * w1;
      ss += __shfl_xor(ss, 1); ss += __shfl_xor(ss, 2);
      ss += __shfl_xor(ss, 4); ss += __shfl_xor(ss, 8);
      if (lm == 0) ssb[wn][rl] = ss;
      // stash w in acc regs (dead) for after-barrier store
      hh[i][0][r] = w0; hh[i][1][r] = w1;
    }
  }
  __syncthreads();
  #pragma unroll
  for (int i = 0; i < 4; ++i) {
    #pragma unroll
    for (int r = 0; r < 4; ++r) {
      const int rl = wm * 64 + i * 16 + lq * 4 + r;
      const int t = mb * 128 + rl;
      const float ss = ssb[0][rl] + ssb[1][rl];
      const float inv = 1.f / fmaxf(sqrtf(ss), 1e-12f);
      half_t* orow = &OUTH[(size_t)(b * Tt + t) * Dd + col0 + 32 * wn + lm];
      orow[0]  = (half_t)(hh[i][0][r] * inv);
      orow[16] = (half_t)(hh[i][1][r] * inv);
    }
  }
}

// ---------------------------------------------------------------------------
// Kernel 2/4: GEMM C[4096,1024] = A@W + bias. M_block=128 (2m waves, a=4),
// N_block=64 (2n waves, b=2). A fp32 (split on fly) or pre-split halves.
// ---------------------------------------------------------------------------
template<bool AF32>
__global__ __launch_bounds__(256, 2) void gemm_frag_kernel(
    const float* __restrict__ A32,
    const half_t* __restrict__ AHI, const half_t* __restrict__ ALO,
    const half_t* __restrict__ WSP, unsigned wbase,
    const float* __restrict__ BIAS, float* __restrict__ OUT)
{
  __shared__ half_t Bs[4096];        // 8 KB: 512 chunks
  const int tid = threadIdx.x;
  const int lane = tid & 63, wave = tid >> 6;
  const int lm = lane & 15, lq = lane >> 4;
  const int wm = wave >> 1, wn = wave & 1;
  const int m0 = blockIdx.x * 128, nb = blockIdx.y;
  const size_t pb = (size_t)wbase + (size_t)nb * 32 * 4096;

  float4v hh[4][2], mx[4][2];
  #pragma unroll
  for (int i = 0; i < 4; ++i)
    #pragma unroll
    for (int t = 0; t < 2; ++t) {
      hh[i][t] = (float4v){0.f, 0.f, 0.f, 0.f};
      mx[i][t] = hh[i][t];
    }

  const size_t arow[4] = {
    (size_t)(m0 + wm * 64 + 0 * 16 + lm) * Dd, (size_t)(m0 + wm * 64 + 1 * 16 + lm) * Dd,
    (size_t)(m0 + wm * 64 + 2 * 16 + lm) * Dd, (size_t)(m0 + wm * 64 + 3 * 16 + lm) * Dd};

  half8 rs[2];
  #pragma unroll
  for (int j = 0; j < 2; ++j)
    rs[j] = *(const half8*)&WSP[pb + (size_t)(tid + j * 256) * 8];

  for (int s = 0; s < 32; ++s) {
    #pragma unroll
    for (int j = 0; j < 2; ++j)
      *(half8*)&Bs[(tid + j * 256) * 8] = rs[j];
    __syncthreads();
    if (s < 31) {
      const size_t nbp = pb + (size_t)(s + 1) * 4096;
      #pragma unroll
      for (int j = 0; j < 2; ++j)
        rs[j] = *(const half8*)&WSP[nbp + (size_t)(tid + j * 256) * 8];
    }
    half8 ahi[4], alo[4];
    #pragma unroll
    for (int i = 0; i < 4; ++i) {
      if constexpr (AF32) {
        float av[8];
        *(float4*)&av[0] = *(const float4*)&A32[arow[i] + s * 32 + lq * 8];
        *(float4*)&av[4] = *(const float4*)&A32[arow[i] + s * 32 + lq * 8 + 4];
        split8(av, ahi[i], alo[i]);
      } else {
        ahi[i] = *(const half8*)&AHI[arow[i] + s * 32 + lq * 8];
        alo[i] = *(const half8*)&ALO[arow[i] + s * 32 + lq * 8];
      }
    }
    #pragma unroll
    for (int t = 0; t < 2; ++t) {
      const int ci = (wn * 2 + t) * 64 + lq * 16 + lm;
      half8 bhi = *(const half8*)&Bs[ci * 8];
      half8 blo = *(const half8*)&Bs[(256 + ci) * 8];
      #pragma unroll
      for (int i = 0; i < 4; ++i) {
        hh[i][t] = MFMA16(ahi[i], bhi, hh[i][t]);
        mx[i][t] = MFMA16(ahi[i], blo, mx[i][t]);
        mx[i][t] = MFMA16(alo[i], bhi, mx[i][t]);
      }
    }
    __syncthreads();
  }

  #pragma unroll
  for (int t = 0; t < 2; ++t) {
    const int col = nb * 64 + (wn * 2 + t) * 16 + lm;
    const float bn = BIAS[col];
    #pragma unroll
    for (int i = 0; i < 4; ++i)
      #pragma unroll
      for (int r = 0; r < 4; ++r) {
        const size_t row = (size_t)(m0 + wm * 64 + i * 16 + lq * 4 + r);
        OUT[row * Dd + col] = hh[i][t][r] + mx[i][t][r] * (1.f / 2048.f) + bn;
      }
  }
}

// ---------------------------------------------------------------------------
// Kernel 3a: G_c[w][d] = sum_{s in c} K[s][w]*V[s][d]. K fp16, V fp32.
// ---------------------------------------------------------------------------
__global__ __launch_bounds__(256) void chunk_kv_kernel(
    const half_t* __restrict__ KNH, const float* __restrict__ V,
    float* __restrict__ G)
{
  __shared__ float Ks[64][64];
  __shared__ float Vs[64][64];
  const int tid = threadIdx.x;
  const int c = blockIdx.x, h = blockIdx.y, b = blockIdx.z;
  const int s0 = c * 64;
  const int lr = tid >> 2, lc = (tid & 3) * 16;
  {
    const half_t* krow = &KNH[(size_t)(b * Tt + s0 + lr) * Dd + h * 64 + lc];
    half8 ka = *(const half8*)&krow[0];
    half8 kb = *(const half8*)&krow[8];
    #pragma unroll
    for (int i = 0; i < 8; ++i) {
      Ks[lr][lc + i] = (float)ka[i];
      Ks[lr][lc + 8 + i] = (float)kb[i];
    }
    const float* vrow = &V[(size_t)(b * Tt + s0 + lr) * Dd + h * 64 + lc];
    #pragma unroll
    for (int i = 0; i < 4; ++i)
      *(float4*)&Vs[lr][lc + i * 4] = *(const float4*)&vrow[i * 4];
  }
  __syncthreads();

  const int ty = tid >> 4, tx = tid & 15;
  float g[4][4] = {{0.f}};
  #pragma unroll 4
  for (int s = 0; s < 64; ++s) {
    float4 kv = *(const float4*)&Ks[s][ty * 4];
    float4 vv = *(const float4*)&Vs[s][tx * 4];
    const float* k_ = (const float*)&kv;
    const float* v_ = (const float*)&vv;
    #pragma unroll
    for (int i = 0; i < 4; ++i)
      #pragma unroll
      for (int j = 0; j < 4; ++j)
        g[i][j] = fmaf(k_[i], v_[j], g[i][j]);
  }
  float* Gp = G + (((size_t)(b * Hh + h) * NC + c) << 12);
  #pragma unroll
  for (int i = 0; i < 4; ++i)
    *(float4*)&Gp[(ty * 4 + i) * 64 + tx * 4] =
        make_float4(g[i][0], g[i][1], g[i][2], g[i][3]);
}

// ---------------------------------------------------------------------------
// Kernel 3b: in-place exclusive prefix over NC chunk matrices per (b,h).
// ---------------------------------------------------------------------------
__global__ __launch_bounds__(256) void prefix_kernel(float* __restrict__ G)
{
  const int h = blockIdx.x, b = blockIdx.y;
  float* base = G + (((size_t)(b * Hh + h) * NC) << 12);
  const int off = threadIdx.x * 16;
  float4 a0 = make_float4(0.f, 0.f, 0.f, 0.f);
  float4 a1 = a0, a2 = a0, a3 = a0;
  for (int c = 0; c < NC; ++c) {
    float* p = base + ((size_t)c << 12) + off;
    float4 g0 = *(float4*)&p[0];
    float4 g1 = *(float4*)&p[4];
    float4 g2 = *(float4*)&p[8];
    float4 g3 = *(float4*)&p[12];
    *(float4*)&p[0] = a0; *(float4*)&p[4] = a1;
    *(float4*)&p[8] = a2; *(float4*)&p[12] = a3;
    a0.x += g0.x; a0.y += g0.y; a0.z += g0.z; a0.w += g0.w;
    a1.x += g1.x; a1.y += g1.y; a1.z += g1.z; a1.w += g1.w;
    a2.x += g2.x; a2.y += g2.y; a2.z += g2.z; a2.w += g2.w;
    a3.x += g3.x; a3.y += g3.y; a3.z += g3.z; a3.w += g3.w;
  }
}

// ---------------------------------------------------------------------------
// Kernel 3c: O_c = (Q_c M_c + tril(Q_c K_c^T) V_c) * scale/sqrt(t+1).
// Q,K fp16 in; out split hi/lo fp16 (lo x2048), aliasing qnh/knh.
// ---------------------------------------------------------------------------
__global__ __launch_bounds__(256) void attn_chunk_kernel(
    const half_t* __restrict__ QNH, const half_t* __restrict__ KNH,
    const float* __restrict__ V, const float* __restrict__ M,
    const float* __restrict__ SCALE,
    half_t* __restrict__ ATTHI, half_t* __restrict__ ATTLO)
{
  __shared__ float Qt[64][68];
  __shared__ float Kt[64][68];
  __shared__ float SM[64][68];
  __shared__ float Vs[64][64];
  const int tid = threadIdx.x;
  const int c = blockIdx.x, h = blockIdx.y, b = blockIdx.z;
  const int t0 = c * 64;
  const int lr = tid >> 2, lc = (tid & 3) * 16;
  {
    const half_t* qrow = &QNH[(size_t)(b * Tt + t0 + lr) * Dd + h * 64 + lc];
    const half_t* krow = &KNH[(size_t)(b * Tt + t0 + lr) * Dd + h * 64 + lc];
    half8 qa = *(const half8*)&qrow[0];
    half8 qb = *(const half8*)&qrow[8];
    half8 ka = *(const half8*)&krow[0];
    half8 kb = *(const half8*)&krow[8];
    #pragma unroll
    for (int i = 0; i < 8; ++i) {
      Qt[lc + i][lr] = (float)qa[i];     Qt[lc + 8 + i][lr] = (float)qb[i];
      Kt[lc + i][lr] = (float)ka[i];     Kt[lc + 8 + i][lr] = (float)kb[i];
    }
    const float* vrow = &V[(size_t)(b * Tt + t0 + lr) * Dd + h * 64 + lc];
    const float* mrow = &M[(((size_t)(b * Hh + h) * NC + c) << 12) + lr * 64 + lc];
    #pragma unroll
    for (int i = 0; i < 4; ++i) {
      *(float4*)&Vs[lr][lc + i * 4] = *(const float4*)&vrow[i * 4];
      *(float4*)&SM[lr][lc + i * 4] = *(const float4*)&mrow[i * 4];
    }
  }
  __syncthreads();

  const int ty = tid >> 4, tx = tid & 15;
  float o[4][4] = {{0.f}};
  float sc[4][4] = {{0.f}};

  #pragma unroll 4
  for (int w = 0; w < 64; ++w) {
    float4 qv = *(const float4*)&Qt[w][ty * 4];
    float4 mv = *(const float4*)&SM[w][tx * 4];
    float4 kv = *(const float4*)&Kt[w][tx * 4];
    const float* q_ = (const float*)&qv;
    const float* m_ = (const float*)&mv;
    const float* k_ = (const float*)&kv;
    #pragma unroll
    for (int i = 0; i < 4; ++i) {
      float qq = q_[i];
      #pragma unroll
      for (int j = 0; j < 4; ++j) {
        o[i][j]  = fmaf(qq, m_[j], o[i][j]);
        sc[i][j] = fmaf(qq, k_[j], sc[i][j]);
      }
    }
  }
  __syncthreads();

  #pragma unroll
  for (int i = 0; i < 4; ++i) {
    const int lt = ty * 4 + i;
    #pragma unroll
    for (int j = 0; j < 4; ++j) {
      const int ls = tx * 4 + j;
      SM[ls][lt] = (ls <= lt) ? sc[i][j] : 0.f;
    }
  }
  __syncthreads();

  #pragma unroll 4
  for (int s = 0; s < 64; ++s) {
    float4 sv = *(const float4*)&SM[s][ty * 4];
    float4 vv = *(const float4*)&Vs[s][tx * 4];
    const float* s_ = (const float*)&sv;
    const float* v_ = (const float*)&vv;
    #pragma unroll
    for (int i = 0; i < 4; ++i)
      #pragma unroll
      for (int j = 0; j < 4; ++j)
        o[i][j] = fmaf(s_[i], v_[j], o[i][j]);
  }

  const float sch = SCALE[h];
  #pragma unroll
  for (int i = 0; i < 4; ++i) {
    const int t = t0 + ty * 4 + i;
    const float fac = sch / sqrtf((float)(t + 1));
    half4h hv, lv;
    #pragma unroll
    for (int j = 0; j < 4; ++j) {
      float v = o[i][j] * fac;
      half_t hx = (half_t)v;
      hv[j] = hx; lv[j] = (half_t)((v - (float)hx) * 2048.f);
    }
    *(half4h*)&ATTHI[(size_t)(b * Tt + t) * Dd + h * 64 + tx * 4] = hv;
    *(half4h*)&ATTLO[(size_t)(b * Tt + t) * Dd + h * 64 + tx * 4] = lv;
  }
}

// ---------------------------------------------------------------------------
extern "C" void kernel_launch(void* const* d_in, const int* in_sizes, int n_in,
                              void* d_out, int out_size, void* d_ws, size_t ws_size,
                              hipStream_t stream) {
  const float* x   = (const float*)d_in[0];
  const float* Wqf = (const float*)d_in[1];
  const float* bqf = (const float*)d_in[2];
  const float* Wkf = (const float*)d_in[3];
  const float* bkf = (const float*)d_in[4];
  const float* Wqp = (const float*)d_in[5];
  const float* bqp = (const float*)d_in[6];
  const float* Wkp = (const float*)d_in[7];
  const float* bkp = (const float*)d_in[8];
  const float* Wv  = (const float*)d_in[9];
  const float* bv  = (const float*)d_in[10];
  const float* Wo  = (const float*)d_in[11];
  const float* bo  = (const float*)d_in[12];
  const float* scale = (const float*)d_in[13];

  // ws layout (56 MB): WSP 24 MB | qnh 8 MB | knh 8 MB | G 16 MB
  half_t* WSP = (half_t*)d_ws;
  half_t* qnh = WSP + 12582912;
  half_t* knh = qnh + 4194304;
  float*  G   = (float*)(knh + 4194304);
  float*  vbuf = (float*)d_out;   // v lives in d_out, consumed before outgemm

  wsplit_kernel<<<dim3(32, 64), 256, 0, stream>>>(Wqf, Wqp, Wkf, Wkp, Wv, Wo, WSP);

  proj_kernel<<<dim3(Tt / 128, Hh, Bb * 2), 256, 0, stream>>>(
      x, WSP, bqf, bqp, bkf, bkp, qnh, knh);

  gemm_frag_kernel<true><<<dim3((Bb * Tt) / 128, 16), 256, 0, stream>>>(
      x, nullptr, nullptr, WSP, VBASE, bv, vbuf);

  chunk_kv_kernel<<<dim3(NC, Hh, Bb), 256, 0, stream>>>(knh, vbuf, G);
  prefix_kernel<<<dim3(Hh, Bb), 256, 0, stream>>>(G);
  attn_chunk_kernel<<<dim3(NC, Hh, Bb), 256, 0, stream>>>(
      qnh, knh, vbuf, G, scale, qnh /*atthi*/, knh /*attlo*/);

  gemm_frag_kernel<false><<<dim3((Bb * Tt) / 128, 16), 256, 0, stream>>>(
      nullptr, qnh, knh, WSP, OBASE, bo, (float*)d_out);
}

// Round 10
// 478.637 us; speedup vs baseline: 1.5815x; 1.0228x over previous
//
#include <hip/hip_runtime.h>

// PureWaveAttention B=2,T=2048,D=1024,H=16,NW=64,HD=64 — fp32 I/O, GEMMs on
// MFMA via 2-term fp16 split: a = hi + lo/2048 (lo stored x2048),
// C = hh(hi,hi) + (mx(hi,lo)+mx(lo,hi))/2048. fp32-equivalent numerics.
// ROUND 10: x pre-split ONCE (xsplit kernel) -> proj/vgemm A-paths are pure
// half8 loads (r9 split8-in-loop was ~160 VALU/slab/wave, repeated 32x).
// B staged in LDS in fragment-linear chunk order (r9, 0 bank conflicts).
// WSP chunk layout per (nb, slab s): [hp(hi/lo)][c = tn*64+lq*16+lm] half8,
//   chunk = W[k=s*32+lq*8 .. +7][col = nb*W + tn*16+lm]  (B-operand frag).
// Regions (halves): Q(qf|qp fused, 128 cols/blk) @0, K @4194304,
//   V(64 cols/blk) @8388608, O @10485760. Total 24 MB.
// Pipeline: wsplit + xsplit -> proj -> vgemm(v in d_out) -> chunk_kv ->
//   prefix -> attn_chunk (att hi/lo fp16, alias qnh/knh) -> outgemm.
// ws (56 MB): WSP 24 | qnh 8 | knh 8 | XG 16 (xhi+xlo, TIME-ALIASED with G:
//   x-halves are dead after vgemm; G written by chunk_kv afterwards).

#define Bb 2
#define Tt 2048
#define Dd 1024
#define Hh 16
#define NC 32

typedef _Float16 half_t;
typedef _Float16 half8 __attribute__((ext_vector_type(8)));
typedef _Float16 half4h __attribute__((ext_vector_type(4)));
typedef float float4v __attribute__((ext_vector_type(4)));

#define MFMA16(a, b, c) __builtin_amdgcn_mfma_f32_16x16x32_f16((a), (b), (c), 0, 0, 0)

#define QBASE 0u
#define KBASE 4194304u
#define VBASE 8388608u
#define OBASE 10485760u

// ---------------------------------------------------------------------------
// Kernel 0a: wsplit -> fragment-linear chunk layout.
// grid (s=32, blk=64): blk 0..15 Q(h), 16..31 K(h), 32..47 V(nb), 48..63 O(nb).
// ---------------------------------------------------------------------------
__global__ __launch_bounds__(256) void wsplit_kernel(
    const float* __restrict__ Wqf, const float* __restrict__ Wqp,
    const float* __restrict__ Wkf, const float* __restrict__ Wkp,
    const float* __restrict__ Wv,  const float* __restrict__ Wo,
    half_t* __restrict__ WSP)
{
  __shared__ float Ld[32][130];
  const int tid = threadIdx.x;
  const int s = blockIdx.x, blk = blockIdx.y;

  const float *SF, *SP;
  size_t baseh; int ncols, hb;
  if (blk < 16)      { hb = blk;      SF = Wqf; SP = Wqp; ncols = 128;
                       baseh = QBASE + (size_t)(hb * 32 + s) * 8192; }
  else if (blk < 32) { hb = blk - 16; SF = Wkf; SP = Wkp; ncols = 128;
                       baseh = KBASE + (size_t)(hb * 32 + s) * 8192; }
  else if (blk < 48) { hb = blk - 32; SF = Wv;  SP = nullptr; ncols = 64;
                       baseh = VBASE + (size_t)(hb * 32 + s) * 4096; }
  else               { hb = blk - 48; SF = Wo;  SP = nullptr; ncols = 64;
                       baseh = OBASE + (size_t)(hb * 32 + s) * 4096; }

  if (ncols == 128) {
    #pragma unroll
    for (int j = 0; j < 4; ++j) {
      const int idx = tid + j * 256;
      const int kr = idx >> 5, c4 = (idx & 31) * 4;
      const float* src = (c4 < 64) ? SF : SP;
      const int cg = hb * 64 + (c4 & 63);
      *(float4*)&Ld[kr][c4] = *(const float4*)&src[(size_t)(s * 32 + kr) * Dd + cg];
    }
  } else {
    #pragma unroll
    for (int j = 0; j < 2; ++j) {
      const int idx = tid + j * 256;
      const int kr = idx >> 4, c4 = (idx & 15) * 4;
      const int cg = hb * 64 + c4;
      *(float4*)&Ld[kr][c4] = *(const float4*)&SF[(size_t)(s * 32 + kr) * Dd + cg];
    }
  }
  __syncthreads();

  const int nch2 = (ncols == 128) ? 1024 : 512;
  const int halfn = nch2 >> 1;
  for (int j = 0; j < 4; ++j) {
    const int idx = tid + j * 256;
    if (idx >= nch2) break;
    const int hp = (idx >= halfn);
    const int c = idx - hp * halfn;
    const int tn = c >> 6, lq = (c >> 4) & 3, lm = c & 15;
    const int col = tn * 16 + lm;
    half8 outv;
    #pragma unroll
    for (int i = 0; i < 8; ++i) {
      float v = Ld[lq * 8 + i][col];
      half_t h = (half_t)v;
      outv[i] = hp ? (half_t)((v - (float)h) * 2048.f) : h;
    }
    *(half8*)&WSP[baseh + (size_t)idx * 8] = outv;
  }
}

// ---------------------------------------------------------------------------
// Kernel 0b: xsplit — x fp32 -> xhi, xlo fp16 (lo x2048). Pure streaming.
// ---------------------------------------------------------------------------
__global__ __launch_bounds__(256) void xsplit_kernel(
    const float* __restrict__ X, half_t* __restrict__ XHI, half_t* __restrict__ XLO)
{
  const size_t i0 = ((size_t)blockIdx.x * 256 + threadIdx.x) * 8;
  float av[8];
  *(float4*)&av[0] = *(const float4*)&X[i0];
  *(float4*)&av[4] = *(const float4*)&X[i0 + 4];
  half8 hv, lv;
  #pragma unroll
  for (int i = 0; i < 8; ++i) {
    half_t h = (half_t)av[i];
    hv[i] = h;
    lv[i] = (half_t)((av[i] - (float)h) * 2048.f);
  }
  *(half8*)&XHI[i0] = hv;
  *(half8*)&XLO[i0] = lv;
}

// ---------------------------------------------------------------------------
// Kernel 1: proj. grid (mb=16, h=16, z=4: b*2+p). 4 waves 2m x 2n.
// Wave (wm,wn): rows wm*64 + i*16+lm (i<4, pre-split halves from global);
// tn set {2wn,2wn+1,2wn+4,2wn+5} -> lane holds matching (f,p) cols.
// Epilogue: sin(f*t+p), cross-wave norm via LDS, fp16 out.
// ---------------------------------------------------------------------------
__global__ __launch_bounds__(256, 2) void proj_kernel(
    const half_t* __restrict__ XHI, const half_t* __restrict__ XLO,
    const half_t* __restrict__ WSP,
    const float* __restrict__ bqf, const float* __restrict__ bqp,
    const float* __restrict__ bkf, const float* __restrict__ bkp,
    half_t* __restrict__ QNH, half_t* __restrict__ KNH)
{
  __shared__ half_t Bs[8192];        // 16 KB: 1024 chunks
  __shared__ float ssb[2][128];
  const int tid = threadIdx.x;
  const int lane = tid & 63, wave = tid >> 6;
  const int lm = lane & 15, lq = lane >> 4;
  const int wm = wave >> 1, wn = wave & 1;
  const int mb = blockIdx.x, h = blockIdx.y;
  const int b = blockIdx.z >> 1, p = blockIdx.z & 1;
  const int col0 = h * 64;
  const size_t pb = (p ? KBASE : QBASE) + (size_t)h * 32 * 8192;
  const float* BF = p ? bkf : bqf;
  const float* BP = p ? bkp : bqp;
  half_t* OUTH = p ? KNH : QNH;

  size_t arow[4];
  #pragma unroll
  for (int i = 0; i < 4; ++i)
    arow[i] = (size_t)(b * Tt + mb * 128 + wm * 64 + i * 16 + lm) * Dd;

  float4v hh[4][4], mx[4][4];
  #pragma unroll
  for (int i = 0; i < 4; ++i)
    #pragma unroll
    for (int t = 0; t < 4; ++t) {
      hh[i][t] = (float4v){0.f, 0.f, 0.f, 0.f};
      mx[i][t] = hh[i][t];
    }

  int tg[4];
  #pragma unroll
  for (int t = 0; t < 4; ++t) tg[t] = 2 * wn + (t & 1) + (t >> 1) * 4;

  half8 rs[4];
  #pragma unroll
  for (int j = 0; j < 4; ++j)
    rs[j] = *(const half8*)&WSP[pb + (size_t)(tid + j * 256) * 8];

  for (int s = 0; s < 32; ++s) {
    #pragma unroll
    for (int j = 0; j < 4; ++j)
      *(half8*)&Bs[(tid + j * 256) * 8] = rs[j];
    __syncthreads();
    if (s < 31) {
      const size_t nb = pb + (size_t)(s + 1) * 8192;
      #pragma unroll
      for (int j = 0; j < 4; ++j)
        rs[j] = *(const half8*)&WSP[nb + (size_t)(tid + j * 256) * 8];
    }
    half8 ahi[4], alo[4];
    #pragma unroll
    for (int i = 0; i < 4; ++i) {
      ahi[i] = *(const half8*)&XHI[arow[i] + s * 32 + lq * 8];
      alo[i] = *(const half8*)&XLO[arow[i] + s * 32 + lq * 8];
    }
    #pragma unroll
    for (int t = 0; t < 4; ++t) {
      const int ci = tg[t] * 64 + lq * 16 + lm;
      half8 bhi = *(const half8*)&Bs[ci * 8];
      half8 blo = *(const half8*)&Bs[(512 + ci) * 8];
      #pragma unroll
      for (int i = 0; i < 4; ++i) {
        hh[i][t] = MFMA16(ahi[i], bhi, hh[i][t]);
        mx[i][t] = MFMA16(ahi[i], blo, mx[i][t]);
        mx[i][t] = MFMA16(alo[i], bhi, mx[i][t]);
      }
    }
    __syncthreads();
  }

  float fb[2], pb2[2];
  #pragma unroll
  for (int e = 0; e < 2; ++e) {
    fb[e]  = BF[col0 + 32 * wn + 16 * e + lm];
    pb2[e] = BP[col0 + 32 * wn + 16 * e + lm];
  }
  #pragma unroll
  for (int i = 0; i < 4; ++i) {
    #pragma unroll
    for (int r = 0; r < 4; ++r) {
      const int rl = wm * 64 + i * 16 + lq * 4 + r;
      const int t = mb * 128 + rl;
      const float tf = (float)t;
      float w0, w1;
      {
        float f0 = hh[i][0][r] + mx[i][0][r] * (1.f / 2048.f) + fb[0];
        float p0 = hh[i][2][r] + mx[i][2][r] * (1.f / 2048.f) + pb2[0];
        w0 = sinf(fmaf(f0, tf, p0));
        float f1 = hh[i][1][r] + mx[i][1][r] * (1.f / 2048.f) + fb[1];
        float p1 = hh[i][3][r] + mx[i][3][r] * (1.f / 2048.f) + pb2[1];
        w1 = sinf(fmaf(f1, tf, p1));
      }
      float ss = w0 * w0 + w1 * w1;
      ss += __shfl_xor(ss, 1); ss += __shfl_xor(ss, 2);
      ss += __shfl_xor(ss, 4); ss += __shfl_xor(ss, 8);
      if (lm == 0) ssb[wn][rl] = ss;
      hh[i][0][r] = w0; hh[i][1][r] = w1;
    }
  }
  __syncthreads();
  #pragma unroll
  for (int i = 0; i < 4; ++i) {
    #pragma unroll
    for (int r = 0; r < 4; ++r) {
      const int rl = wm * 64 + i * 16 + lq * 4 + r;
      const int t = mb * 128 + rl;
      const float ss = ssb[0][rl] + ssb[1][rl];
      const float inv = 1.f / fmaxf(sqrtf(ss), 1e-12f);
      half_t* orow = &OUTH[(size_t)(b * Tt + t) * Dd + col0 + 32 * wn + lm];
      orow[0]  = (half_t)(hh[i][0][r] * inv);
      orow[16] = (half_t)(hh[i][1][r] * inv);
    }
  }
}

// ---------------------------------------------------------------------------
// Kernel 2/4: GEMM C[4096,1024] = A@W + bias. M_block=128 (2m waves, a=4),
// N_block=64 (2n waves, b=2). A from pre-split halves.
// ---------------------------------------------------------------------------
__global__ __launch_bounds__(256, 2) void gemm_frag_kernel(
    const half_t* __restrict__ AHI, const half_t* __restrict__ ALO,
    const half_t* __restrict__ WSP, unsigned wbase,
    const float* __restrict__ BIAS, float* __restrict__ OUT)
{
  __shared__ half_t Bs[4096];        // 8 KB: 512 chunks
  const int tid = threadIdx.x;
  const int lane = tid & 63, wave = tid >> 6;
  const int lm = lane & 15, lq = lane >> 4;
  const int wm = wave >> 1, wn = wave & 1;
  const int m0 = blockIdx.x * 128, nb = blockIdx.y;
  const size_t pb = (size_t)wbase + (size_t)nb * 32 * 4096;

  float4v hh[4][2], mx[4][2];
  #pragma unroll
  for (int i = 0; i < 4; ++i)
    #pragma unroll
    for (int t = 0; t < 2; ++t) {
      hh[i][t] = (float4v){0.f, 0.f, 0.f, 0.f};
      mx[i][t] = hh[i][t];
    }

  const size_t arow[4] = {
    (size_t)(m0 + wm * 64 + 0 * 16 + lm) * Dd, (size_t)(m0 + wm * 64 + 1 * 16 + lm) * Dd,
    (size_t)(m0 + wm * 64 + 2 * 16 + lm) * Dd, (size_t)(m0 + wm * 64 + 3 * 16 + lm) * Dd};

  half8 rs[2];
  #pragma unroll
  for (int j = 0; j < 2; ++j)
    rs[j] = *(const half8*)&WSP[pb + (size_t)(tid + j * 256) * 8];

  for (int s = 0; s < 32; ++s) {
    #pragma unroll
    for (int j = 0; j < 2; ++j)
      *(half8*)&Bs[(tid + j * 256) * 8] = rs[j];
    __syncthreads();
    if (s < 31) {
      const size_t nbp = pb + (size_t)(s + 1) * 4096;
      #pragma unroll
      for (int j = 0; j < 2; ++j)
        rs[j] = *(const half8*)&WSP[nbp + (size_t)(tid + j * 256) * 8];
    }
    half8 ahi[4], alo[4];
    #pragma unroll
    for (int i = 0; i < 4; ++i) {
      ahi[i] = *(const half8*)&AHI[arow[i] + s * 32 + lq * 8];
      alo[i] = *(const half8*)&ALO[arow[i] + s * 32 + lq * 8];
    }
    #pragma unroll
    for (int t = 0; t < 2; ++t) {
      const int ci = (wn * 2 + t) * 64 + lq * 16 + lm;
      half8 bhi = *(const half8*)&Bs[ci * 8];
      half8 blo = *(const half8*)&Bs[(256 + ci) * 8];
      #pragma unroll
      for (int i = 0; i < 4; ++i) {
        hh[i][t] = MFMA16(ahi[i], bhi, hh[i][t]);
        mx[i][t] = MFMA16(ahi[i], blo, mx[i][t]);
        mx[i][t] = MFMA16(alo[i], bhi, mx[i][t]);
      }
    }
    __syncthreads();
  }

  #pragma unroll
  for (int t = 0; t < 2; ++t) {
    const int col = nb * 64 + (wn * 2 + t) * 16 + lm;
    const float bn = BIAS[col];
    #pragma unroll
    for (int i = 0; i < 4; ++i)
      #pragma unroll
      for (int r = 0; r < 4; ++r) {
        const size_t row = (size_t)(m0 + wm * 64 + i * 16 + lq * 4 + r);
        OUT[row * Dd + col] = hh[i][t][r] + mx[i][t][r] * (1.f / 2048.f) + bn;
      }
  }
}

// ---------------------------------------------------------------------------
// Kernel 3a: G_c[w][d] = sum_{s in c} K[s][w]*V[s][d]. K fp16, V fp32.
// ---------------------------------------------------------------------------
__global__ __launch_bounds__(256) void chunk_kv_kernel(
    const half_t* __restrict__ KNH, const float* __restrict__ V,
    float* __restrict__ G)
{
  __shared__ float Ks[64][64];
  __shared__ float Vs[64][64];
  const int tid = threadIdx.x;
  const int c = blockIdx.x, h = blockIdx.y, b = blockIdx.z;
  const int s0 = c * 64;
  const int lr = tid >> 2, lc = (tid & 3) * 16;
  {
    const half_t* krow = &KNH[(size_t)(b * Tt + s0 + lr) * Dd + h * 64 + lc];
    half8 ka = *(const half8*)&krow[0];
    half8 kb = *(const half8*)&krow[8];
    #pragma unroll
    for (int i = 0; i < 8; ++i) {
      Ks[lr][lc + i] = (float)ka[i];
      Ks[lr][lc + 8 + i] = (float)kb[i];
    }
    const float* vrow = &V[(size_t)(b * Tt + s0 + lr) * Dd + h * 64 + lc];
    #pragma unroll
    for (int i = 0; i < 4; ++i)
      *(float4*)&Vs[lr][lc + i * 4] = *(const float4*)&vrow[i * 4];
  }
  __syncthreads();

  const int ty = tid >> 4, tx = tid & 15;
  float g[4][4] = {{0.f}};
  #pragma unroll 4
  for (int s = 0; s < 64; ++s) {
    float4 kv = *(const float4*)&Ks[s][ty * 4];
    float4 vv = *(const float4*)&Vs[s][tx * 4];
    const float* k_ = (const float*)&kv;
    const float* v_ = (const float*)&vv;
    #pragma unroll
    for (int i = 0; i < 4; ++i)
      #pragma unroll
      for (int j = 0; j < 4; ++j)
        g[i][j] = fmaf(k_[i], v_[j], g[i][j]);
  }
  float* Gp = G + (((size_t)(b * Hh + h) * NC + c) << 12);
  #pragma unroll
  for (int i = 0; i < 4; ++i)
    *(float4*)&Gp[(ty * 4 + i) * 64 + tx * 4] =
        make_float4(g[i][0], g[i][1], g[i][2], g[i][3]);
}

// ---------------------------------------------------------------------------
// Kernel 3b: in-place exclusive prefix over NC chunk matrices per (b,h).
// ---------------------------------------------------------------------------
__global__ __launch_bounds__(256) void prefix_kernel(float* __restrict__ G)
{
  const int h = blockIdx.x, b = blockIdx.y;
  float* base = G + (((size_t)(b * Hh + h) * NC) << 12);
  const int off = threadIdx.x * 16;
  float4 a0 = make_float4(0.f, 0.f, 0.f, 0.f);
  float4 a1 = a0, a2 = a0, a3 = a0;
  for (int c = 0; c < NC; ++c) {
    float* p = base + ((size_t)c << 12) + off;
    float4 g0 = *(float4*)&p[0];
    float4 g1 = *(float4*)&p[4];
    float4 g2 = *(float4*)&p[8];
    float4 g3 = *(float4*)&p[12];
    *(float4*)&p[0] = a0; *(float4*)&p[4] = a1;
    *(float4*)&p[8] = a2; *(float4*)&p[12] = a3;
    a0.x += g0.x; a0.y += g0.y; a0.z += g0.z; a0.w += g0.w;
    a1.x += g1.x; a1.y += g1.y; a1.z += g1.z; a1.w += g1.w;
    a2.x += g2.x; a2.y += g2.y; a2.z += g2.z; a2.w += g2.w;
    a3.x += g3.x; a3.y += g3.y; a3.z += g3.z; a3.w += g3.w;
  }
}

// ---------------------------------------------------------------------------
// Kernel 3c: O_c = (Q_c M_c + tril(Q_c K_c^T) V_c) * scale/sqrt(t+1).
// Q,K fp16 in; out split hi/lo fp16 (lo x2048), aliasing qnh/knh.
// ---------------------------------------------------------------------------
__global__ __launch_bounds__(256) void attn_chunk_kernel(
    const half_t* __restrict__ QNH, const half_t* __restrict__ KNH,
    const float* __restrict__ V, const float* __restrict__ M,
    const float* __restrict__ SCALE,
    half_t* __restrict__ ATTHI, half_t* __restrict__ ATTLO)
{
  __shared__ float Qt[64][68];
  __shared__ float Kt[64][68];
  __shared__ float SM[64][68];
  __shared__ float Vs[64][64];
  const int tid = threadIdx.x;
  const int c = blockIdx.x, h = blockIdx.y, b = blockIdx.z;
  const int t0 = c * 64;
  const int lr = tid >> 2, lc = (tid & 3) * 16;
  {
    const half_t* qrow = &QNH[(size_t)(b * Tt + t0 + lr) * Dd + h * 64 + lc];
    const half_t* krow = &KNH[(size_t)(b * Tt + t0 + lr) * Dd + h * 64 + lc];
    half8 qa = *(const half8*)&qrow[0];
    half8 qb = *(const half8*)&qrow[8];
    half8 ka = *(const half8*)&krow[0];
    half8 kb = *(const half8*)&krow[8];
    #pragma unroll
    for (int i = 0; i < 8; ++i) {
      Qt[lc + i][lr] = (float)qa[i];     Qt[lc + 8 + i][lr] = (float)qb[i];
      Kt[lc + i][lr] = (float)ka[i];     Kt[lc + 8 + i][lr] = (float)kb[i];
    }
    const float* vrow = &V[(size_t)(b * Tt + t0 + lr) * Dd + h * 64 + lc];
    const float* mrow = &M[(((size_t)(b * Hh + h) * NC + c) << 12) + lr * 64 + lc];
    #pragma unroll
    for (int i = 0; i < 4; ++i) {
      *(float4*)&Vs[lr][lc + i * 4] = *(const float4*)&vrow[i * 4];
      *(float4*)&SM[lr][lc + i * 4] = *(const float4*)&mrow[i * 4];
    }
  }
  __syncthreads();

  const int ty = tid >> 4, tx = tid & 15;
  float o[4][4] = {{0.f}};
  float sc[4][4] = {{0.f}};

  #pragma unroll 4
  for (int w = 0; w < 64; ++w) {
    float4 qv = *(const float4*)&Qt[w][ty * 4];
    float4 mv = *(const float4*)&SM[w][tx * 4];
    float4 kv = *(const float4*)&Kt[w][tx * 4];
    const float* q_ = (const float*)&qv;
    const float* m_ = (const float*)&mv;
    const float* k_ = (const float*)&kv;
    #pragma unroll
    for (int i = 0; i < 4; ++i) {
      float qq = q_[i];
      #pragma unroll
      for (int j = 0; j < 4; ++j) {
        o[i][j]  = fmaf(qq, m_[j], o[i][j]);
        sc[i][j] = fmaf(qq, k_[j], sc[i][j]);
      }
    }
  }
  __syncthreads();

  #pragma unroll
  for (int i = 0; i < 4; ++i) {
    const int lt = ty * 4 + i;
    #pragma unroll
    for (int j = 0; j < 4; ++j) {
      const int ls = tx * 4 + j;
      SM[ls][lt] = (ls <= lt) ? sc[i][j] : 0.f;
    }
  }
  __syncthreads();

  #pragma unroll 4
  for (int s = 0; s < 64; ++s) {
    float4 sv = *(const float4*)&SM[s][ty * 4];
    float4 vv = *(const float4*)&Vs[s][tx * 4];
    const float* s_ = (const float*)&sv;
    const float* v_ = (const float*)&vv;
    #pragma unroll
    for (int i = 0; i < 4; ++i)
      #pragma unroll
      for (int j = 0; j < 4; ++j)
        o[i][j] = fmaf(s_[i], v_[j], o[i][j]);
  }

  const float sch = SCALE[h];
  #pragma unroll
  for (int i = 0; i < 4; ++i) {
    const int t = t0 + ty * 4 + i;
    const float fac = sch / sqrtf((float)(t + 1));
    half4h hv, lv;
    #pragma unroll
    for (int j = 0; j < 4; ++j) {
      float v = o[i][j] * fac;
      half_t hx = (half_t)v;
      hv[j] = hx; lv[j] = (half_t)((v - (float)hx) * 2048.f);
    }
    *(half4h*)&ATTHI[(size_t)(b * Tt + t) * Dd + h * 64 + tx * 4] = hv;
    *(half4h*)&ATTLO[(size_t)(b * Tt + t) * Dd + h * 64 + tx * 4] = lv;
  }
}

// ---------------------------------------------------------------------------
extern "C" void kernel_launch(void* const* d_in, const int* in_sizes, int n_in,
                              void* d_out, int out_size, void* d_ws, size_t ws_size,
                              hipStream_t stream) {
  const float* x   = (const float*)d_in[0];
  const float* Wqf = (const float*)d_in[1];
  const float* bqf = (const float*)d_in[2];
  const float* Wkf = (const float*)d_in[3];
  const float* bkf = (const float*)d_in[4];
  const float* Wqp = (const float*)d_in[5];
  const float* bqp = (const float*)d_in[6];
  const float* Wkp = (const float*)d_in[7];
  const float* bkp = (const float*)d_in[8];
  const float* Wv  = (const float*)d_in[9];
  const float* bv  = (const float*)d_in[10];
  const float* Wo  = (const float*)d_in[11];
  const float* bo  = (const float*)d_in[12];
  const float* scale = (const float*)d_in[13];

  // ws (56 MB): WSP 24 | qnh 8 | knh 8 | XG 16 (xhi 8 + xlo 8, later G)
  half_t* WSP = (half_t*)d_ws;
  half_t* qnh = WSP + 12582912;
  half_t* knh = qnh + 4194304;
  half_t* xhi = knh + 4194304;
  half_t* xlo = xhi + 4194304;
  float*  G   = (float*)xhi;      // TIME-ALIAS: xhi/xlo dead after vgemm
  float*  vbuf = (float*)d_out;   // v in d_out, consumed before outgemm

  wsplit_kernel<<<dim3(32, 64), 256, 0, stream>>>(Wqf, Wqp, Wkf, Wkp, Wv, Wo, WSP);
  xsplit_kernel<<<dim3((Bb * Tt * Dd) / 2048), 256, 0, stream>>>(x, xhi, xlo);

  proj_kernel<<<dim3(Tt / 128, Hh, Bb * 2), 256, 0, stream>>>(
      xhi, xlo, WSP, bqf, bqp, bkf, bkp, qnh, knh);

  gemm_frag_kernel<<<dim3((Bb * Tt) / 128, 16), 256, 0, stream>>>(
      xhi, xlo, WSP, VBASE, bv, vbuf);

  chunk_kv_kernel<<<dim3(NC, Hh, Bb), 256, 0, stream>>>(knh, vbuf, G);
  prefix_kernel<<<dim3(Hh, Bb), 256, 0, stream>>>(G);
  attn_chunk_kernel<<<dim3(NC, Hh, Bb), 256, 0, stream>>>(
      qnh, knh, vbuf, G, scale, qnh /*atthi*/, knh /*attlo*/);

  gemm_frag_kernel<<<dim3((Bb * Tt) / 128, 16), 256, 0, stream>>>(
      qnh, knh, WSP, OBASE, bo, (float*)d_out);
}